// Round 6
// baseline (19.551 us; speedup 1.0000x reference)
//
#include <hip/hip_runtime.h>

typedef _Float16 f16x8 __attribute__((ext_vector_type(8)));
typedef float    f32x4 __attribute__((ext_vector_type(4)));

#define S    512
#define CIN  16
#define COUT 16

static __device__ inline unsigned int pkrtz(float lo, float hi) {
    auto h = __builtin_amdgcn_cvt_pkrtz(lo, hi);   // __fp16 ext_vector(2)
    return __builtin_bit_cast(unsigned int, h);
}

// ---- kernel 1: feat [4][512][16] f32 -> ws [4][16][512] fp16 (plain b-linear) ----
__global__ __launch_bounds__(256)
void transpose_feat(const float* __restrict__ feat, unsigned short* __restrict__ ft)
{
    const int id = blockIdx.x * 256 + threadIdx.x;   // 0..16383
    const int bp = id & 255;                         // b-pair
    const int j  = (id >> 8) & 15;
    const int z  = id >> 12;
    const float* fz = feat + z * S * CIN;
    float f0 = fz[(2 * bp)     * CIN + j];
    float f1 = fz[(2 * bp + 1) * CIN + j];
    *(unsigned int*)((char*)ft + z * 16384 + j * 1024 + 4 * bp) = pkrtz(f0, f1);
}

// ---- main: grid 512 (4 z * 128 a-quads), 4 waves, one a per wave, NO barriers ----
// T[rm,j] = sum_b Bas[b,rm]*F[b,j] via mfma_f32_16x16x32_f16.
//   A = Bas^T per-wave LDS [32 rm][128 b] fp16, XOR-swizzled (write 2-way free)
//   B = F^T fp16 read straight from global (L2-hot, plain layout)
// Plain-B + swizzled-A enumerate the same k-order (XOR cancels within 16B runs).
__global__ __launch_bounds__(256, 2)
void econv_mfma(const float* __restrict__ geom,            // [4][512][3]
                const unsigned short* __restrict__ ft,     // [4][16][512] fp16
                const float* __restrict__ Wm,              // [32 rm][16 i][16 j]
                const int*   __restrict__ n_norm,          // [1]
                float*       __restrict__ out)             // [4][512][16]
{
    __shared__ unsigned short BasU[4 * 32 * 128];   // 32 KB, 8 KB per wave

    const int t = threadIdx.x;
    const int z = blockIdx.x >> 7;
    const int a0 = (blockIdx.x & 127) << 2;
    const int w = t >> 6;
    const int l = t & 63;
    const int a = a0 + w;

    const float* gz = geom + z * S * 3;
    const char*  Fg = (const char*)ft + z * 16384;

    const float gax = gz[3 * a], gay = gz[3 * a + 1], gaz = gz[3 * a + 2];

    char* BasB = (char*)BasU + w * 8192;
    const int mrow = l & 15;            // rm row (tile0) == F^T row j == out i
    const int g    = l >> 4;
    const int rkey = (mrow & 7) << 4;   // read swizzle key (same for mrow+16)
    const unsigned int wb = 4 * l;      // write byte base within 256B Bas row

    f32x4 acc0 = {0.f, 0.f, 0.f, 0.f};
    f32x4 acc1 = {0.f, 0.f, 0.f, 0.f};

#pragma unroll
    for (int c = 0; c < 4; ++c) {
        const int b = c * 128 + 2 * l;          // this lane's b pair
        const float* gp = gz + 3 * b;           // 24l-byte offset: 8-aligned
        float2 q0 = *(const float2*)(gp);       // gx0 gy0
        float2 q1 = *(const float2*)(gp + 2);   // gz0 gx1
        float2 q2 = *(const float2*)(gp + 4);   // gy1 gz1

        float dx0 = q0.x - gax, dy0 = q0.y - gay, dz0 = q1.x - gaz;
        float dx1 = q1.y - gax, dy1 = q2.x - gay, dz1 = q2.y - gaz;
        float ss0 = fmaf(dx0, dx0, fmaf(dy0, dy0, fmaf(dz0, dz0, 1e-12f)));
        float ss1 = fmaf(dx1, dx1, fmaf(dy1, dy1, fmaf(dz1, dz1, 1e-12f)));
        float inv0 = rsqrtf(ss0), inv1 = rsqrtf(ss1);
        float dd0 = ss0 * inv0,  dd1 = ss1 * inv1;
        float ux0 = dx0 * inv0, uy0 = dy0 * inv0, uz0 = dz0 * inv0;
        float ux1 = dx1 * inv1, uy1 = dy1 * inv1, uz1 = dz1 * inv1;

        unsigned int pw[32];
#pragma unroll
        for (int r = 0; r < 8; ++r) {
            const float cen = (float)r * (3.0f / 7.0f);
            float e0 = dd0 - cen, e1 = dd1 - cen;
            float rad0 = __expf(-8.0f * e0 * e0);
            float rad1 = __expf(-8.0f * e1 * e1);
            pw[4 * r + 0] = pkrtz(rad0,       rad1);
            pw[4 * r + 1] = pkrtz(rad0 * ux0, rad1 * ux1);
            pw[4 * r + 2] = pkrtz(rad0 * uy0, rad1 * uy1);
            pw[4 * r + 3] = pkrtz(rad0 * uz0, rad1 * uz1);
        }
        // scatter 32 rm rows for this lane's b pair, swizzled (2-way max -> free)
#pragma unroll
        for (int rm = 0; rm < 32; ++rm) {
            *(unsigned int*)(BasB + rm * 256 + (wb ^ ((rm & 7) << 4))) = pw[rm];
        }

        // 4 k-steps of MFMA over this 128-b chunk; B-frags straight from global
#pragma unroll
        for (int ks = 0; ks < 4; ++ks) {
            const int colb = 64 * ks + 16 * g;
            f16x8 A0 = *(f16x8*)(BasB + mrow * 256        + (colb ^ rkey));
            f16x8 A1 = *(f16x8*)(BasB + (mrow + 16) * 256 + (colb ^ rkey));
            f16x8 Bf = *(const f16x8*)(Fg + mrow * 1024 + c * 256 + colb);
            acc0 = __builtin_amdgcn_mfma_f32_16x16x32_f16(A0, Bf, acc0, 0, 0, 0);
            acc1 = __builtin_amdgcn_mfma_f32_16x16x32_f16(A1, Bf, acc1, 0, 0, 0);
        }
    }

    // ---- epilogue (wave-local, in-order LDS, no barrier): T then W contraction ----
    float* Tl = (float*)BasB;   // [32 rm][16 j] f32 = 2 KB
#pragma unroll
    for (int q = 0; q < 4; ++q) {
        Tl[(4 * g + q) * 16 + mrow]      = acc0[q];
        Tl[(16 + 4 * g + q) * 16 + mrow] = acc1[q];
    }

    float o = 0.f;
#pragma unroll
    for (int rr = 0; rr < 8; ++rr) {
        const int row = g * 8 + rr;
#pragma unroll
        for (int j4 = 0; j4 < 4; ++j4) {
            f32x4 tv = *(const f32x4*)(Tl + row * 16 + 4 * j4);
            f32x4 wv = *(const f32x4*)(Wm + row * 256 + mrow * 16 + 4 * j4);
            o = fmaf(tv[0], wv[0], o);
            o = fmaf(tv[1], wv[1], o);
            o = fmaf(tv[2], wv[2], o);
            o = fmaf(tv[3], wv[3], o);
        }
    }
    o += __shfl_xor(o, 16);
    o += __shfl_xor(o, 32);
    if (l < 16) {
        const float scale = rsqrtf((float)n_norm[0]);   // 1/sqrt(512)
        out[(z * S + a) * COUT + mrow] = o * scale;
    }
}

extern "C" void kernel_launch(void* const* d_in, const int* in_sizes, int n_in,
                              void* d_out, int out_size, void* d_ws, size_t ws_size,
                              hipStream_t stream) {
    const float* feat   = (const float*)d_in[0];
    const float* geomp  = (const float*)d_in[1];
    const float* Wm     = (const float*)d_in[2];
    const int*   n_norm = (const int*)d_in[3];
    float* outp = (float*)d_out;
    unsigned short* ftp = (unsigned short*)d_ws;   // 64 KB used

    transpose_feat<<<dim3(64), dim3(256), 0, stream>>>(feat, ftp);
    econv_mfma<<<dim3(512), dim3(256), 0, stream>>>(geomp, ftp, Wm, n_norm, outp);
}

// Round 7
// 13.729 us; speedup vs baseline: 1.4241x; 1.4241x over previous
//
#include <hip/hip_runtime.h>

typedef _Float16 f16x8 __attribute__((ext_vector_type(8)));
typedef float    f32x4 __attribute__((ext_vector_type(4)));

#define S 512

static __device__ inline unsigned int pkrtz(float lo, float hi) {
    auto h = __builtin_amdgcn_cvt_pkrtz(lo, hi);   // __fp16 ext_vector(2)
    return __builtin_bit_cast(unsigned int, h);
}

// grid: 4 z * 128 a-quads = 512 blocks (2/CU), 4 waves, one a per wave.
// T[rm,j] = sum_b Bas[b,rm]*F[b,j] via mfma_f32_16x16x32_f16, K=512 in
// 2 chunks of 256 b.
//   A = Bas^T per-wave LDS [32 rm][256 b] fp16, XOR-swizzled, b64 writes
//   B = F^T   per-block LDS [16 j][512 b] fp16, XOR-swizzled (staged once)
// Lane owns 4 consecutive b's per chunk -> geometry is 3 float4 global loads
// per chunk (prefetched for both chunks up front), basis rows written as
// uint2 (ds_write_b64). Swizzle algebra: write slot (8l)^key vs read
// 16B @ col^key gives ascending b = col/2..col/2+7, matching the plain
// ascending b-order of the F^T fragment at the same col (R4/R6-validated).
__global__ __launch_bounds__(256, 2)
void econv_mfma(const float* __restrict__ feat,   // [4][512][16]
                const float* __restrict__ geom,   // [4][512][3]
                const float* __restrict__ Wm,     // [32 rm][16 i][16 j]
                const int*   __restrict__ n_norm, // [1]
                float*       __restrict__ out)    // [4][512][16]
{
    __shared__ unsigned short FtU[16 * S];        // 16 KB  F^T fp16, swizzled
    __shared__ unsigned short BasU[4 * 32 * 256]; // 64 KB  per-wave Bas^T (reused as T)

    const int t = threadIdx.x;
    const int z = blockIdx.x >> 7;
    const int a0 = (blockIdx.x & 127) << 2;
    const int w = t >> 6;
    const int l = t & 63;
    const int a = a0 + w;

    const float* gz = geom + z * S * 3;
    const float* fz = feat + z * S * 16;

    // ---- issue F-staging loads first (this thread owns b-pair 2t, 2t+1) ----
    const float* fp = fz + 32 * t;
    f32x4 fa0 = *(const f32x4*)(fp +  0);
    f32x4 fa1 = *(const f32x4*)(fp +  4);
    f32x4 fa2 = *(const f32x4*)(fp +  8);
    f32x4 fa3 = *(const f32x4*)(fp + 12);
    f32x4 fb0 = *(const f32x4*)(fp + 16);
    f32x4 fb1 = *(const f32x4*)(fp + 20);
    f32x4 fb2 = *(const f32x4*)(fp + 24);
    f32x4 fb3 = *(const f32x4*)(fp + 28);

    // ---- issue geometry prefetch for both chunks (4 b's per lane each) ----
    // chunk c: b = c*256 + 4l .. +3  -> floats gz + 768c + 12l, 3 x float4
    f32x4 gq00 = *(const f32x4*)(gz + 12 * l);
    f32x4 gq01 = *(const f32x4*)(gz + 12 * l + 4);
    f32x4 gq02 = *(const f32x4*)(gz + 12 * l + 8);
    f32x4 gq10 = *(const f32x4*)(gz + 768 + 12 * l);
    f32x4 gq11 = *(const f32x4*)(gz + 768 + 12 * l + 4);
    f32x4 gq12 = *(const f32x4*)(gz + 768 + 12 * l + 8);

    const float gax = gz[3 * a], gay = gz[3 * a + 1], gaz = gz[3 * a + 2];

    // ---- write F^T fp16 swizzled: u32 (b-pair) at row j, byte (4t)^((j&7)<<4) ----
    {
        char* FtB = (char*)FtU;
        const int wb = 4 * t;
#define STJ(Q, JJ, FA, FB) \
        *(unsigned int*)(FtB + (4*Q+JJ) * 1024 + (wb ^ (((4*Q+JJ) & 7) << 4))) = \
            pkrtz(FA[JJ], FB[JJ]);
        STJ(0, 0, fa0, fb0) STJ(0, 1, fa0, fb0) STJ(0, 2, fa0, fb0) STJ(0, 3, fa0, fb0)
        STJ(1, 0, fa1, fb1) STJ(1, 1, fa1, fb1) STJ(1, 2, fa1, fb1) STJ(1, 3, fa1, fb1)
        STJ(2, 0, fa2, fb2) STJ(2, 1, fa2, fb2) STJ(2, 2, fa2, fb2) STJ(2, 3, fa2, fb2)
        STJ(3, 0, fa3, fb3) STJ(3, 1, fa3, fb3) STJ(3, 2, fa3, fb3) STJ(3, 3, fa3, fb3)
#undef STJ
    }
    __syncthreads();   // only barrier; waves independent afterwards

    char* BasB = (char*)BasU + w * 16384;   // this wave's 16 KB slice
    char* FtB  = (char*)FtU;

    const int mrow = l & 15;            // rm row (tile0) == F^T row j == out i
    const int g    = l >> 4;
    const int rkey = (mrow & 7) << 4;   // read swizzle key (same for mrow+16)
    const int wbb  = 8 * l;             // write byte base within 512B Bas row

    f32x4 acc0 = {0.f, 0.f, 0.f, 0.f};
    f32x4 acc1 = {0.f, 0.f, 0.f, 0.f};

#pragma unroll
    for (int c = 0; c < 2; ++c) {
        f32x4 g0 = c ? gq10 : gq00;   // x0 y0 z0 x1
        f32x4 g1 = c ? gq11 : gq01;   // y1 z1 x2 y2
        f32x4 g2 = c ? gq12 : gq02;   // z2 x3 y3 z3

        float dx[4] = {g0[0] - gax, g0[3] - gax, g1[2] - gax, g2[1] - gax};
        float dy[4] = {g0[1] - gay, g1[0] - gay, g1[3] - gay, g2[2] - gay};
        float dz[4] = {g0[2] - gaz, g1[1] - gaz, g2[0] - gaz, g2[3] - gaz};

        float dsq[4], ux[4], uy[4], uz[4];
#pragma unroll
        for (int b = 0; b < 4; ++b) {
            float ss  = fmaf(dx[b], dx[b], fmaf(dy[b], dy[b], fmaf(dz[b], dz[b], 1e-12f)));
            float inv = rsqrtf(ss);
            dsq[b] = (ss * inv) * 2.82842712f;   // sqrt(8) * d
            ux[b] = dx[b] * inv; uy[b] = dy[b] * inv; uz[b] = dz[b] * inv;
        }

        // ---- basis rows: rad_r = exp(-(sqrt8*d - sqrt8*c_r)^2), b64 writes ----
#pragma unroll
        for (int r = 0; r < 8; ++r) {
            const float cs = (float)r * 1.21218305f;   // (3/7)*sqrt(8)*r
            float rd[4];
#pragma unroll
            for (int b = 0; b < 4; ++b) {
                float e = dsq[b] - cs;
                rd[b] = __expf(-(e * e));
            }
            uint2 p;
            p.x = pkrtz(rd[0], rd[1]);           p.y = pkrtz(rd[2], rd[3]);
            *(uint2*)(BasB + (4*r+0) * 512 + (wbb ^ (((4*r+0) & 7) << 4))) = p;
            p.x = pkrtz(rd[0]*ux[0], rd[1]*ux[1]); p.y = pkrtz(rd[2]*ux[2], rd[3]*ux[3]);
            *(uint2*)(BasB + (4*r+1) * 512 + (wbb ^ (((4*r+1) & 7) << 4))) = p;
            p.x = pkrtz(rd[0]*uy[0], rd[1]*uy[1]); p.y = pkrtz(rd[2]*uy[2], rd[3]*uy[3]);
            *(uint2*)(BasB + (4*r+2) * 512 + (wbb ^ (((4*r+2) & 7) << 4))) = p;
            p.x = pkrtz(rd[0]*uz[0], rd[1]*uz[1]); p.y = pkrtz(rd[2]*uz[2], rd[3]*uz[3]);
            *(uint2*)(BasB + (4*r+3) * 512 + (wbb ^ (((4*r+3) & 7) << 4))) = p;
        }

        // ---- 8 k-steps of MFMA over this 256-b chunk ----
#pragma unroll
        for (int ks = 0; ks < 8; ++ks) {
            const int col = 64 * ks + 16 * g;
            f16x8 A0 = *(f16x8*)(BasB + mrow * 512        + (col ^ rkey));
            f16x8 A1 = *(f16x8*)(BasB + (mrow + 16) * 512 + (col ^ rkey));
            f16x8 Bf = *(f16x8*)(FtB + mrow * 1024 + ((c * 512 + col) ^ rkey));
            acc0 = __builtin_amdgcn_mfma_f32_16x16x32_f16(A0, Bf, acc0, 0, 0, 0);
            acc1 = __builtin_amdgcn_mfma_f32_16x16x32_f16(A1, Bf, acc1, 0, 0, 0);
        }
    }

    // ---- epilogue (wave-local, no barrier): T then W contraction ----
    float* Tl = (float*)BasB;   // [32 rm][16 j] f32 = 2 KB
#pragma unroll
    for (int q = 0; q < 4; ++q) {
        Tl[(4 * g + q) * 16 + mrow]      = acc0[q];
        Tl[(16 + 4 * g + q) * 16 + mrow] = acc1[q];
    }

    float o = 0.f;
#pragma unroll
    for (int rr = 0; rr < 8; ++rr) {
        const int row = g * 8 + rr;
#pragma unroll
        for (int j4 = 0; j4 < 4; ++j4) {
            f32x4 tv = *(const f32x4*)(Tl + row * 16 + 4 * j4);
            f32x4 wv = *(const f32x4*)(Wm + row * 256 + mrow * 16 + 4 * j4);
            o = fmaf(tv[0], wv[0], o);
            o = fmaf(tv[1], wv[1], o);
            o = fmaf(tv[2], wv[2], o);
            o = fmaf(tv[3], wv[3], o);
        }
    }
    o += __shfl_xor(o, 16);
    o += __shfl_xor(o, 32);
    if (l < 16) {
        const float scale = rsqrtf((float)n_norm[0]);   // 1/sqrt(512)
        out[(z * S + a) * 16 + mrow] = o * scale;
    }
}

extern "C" void kernel_launch(void* const* d_in, const int* in_sizes, int n_in,
                              void* d_out, int out_size, void* d_ws, size_t ws_size,
                              hipStream_t stream) {
    const float* feat   = (const float*)d_in[0];
    const float* geomp  = (const float*)d_in[1];
    const float* Wm     = (const float*)d_in[2];
    const int*   n_norm = (const int*)d_in[3];
    float* outp = (float*)d_out;

    econv_mfma<<<dim3(512), dim3(256), 0, stream>>>(feat, geomp, Wm, n_norm, outp);
}